// Round 5
// baseline (195.921 us; speedup 1.0000x reference)
//
#include <hip/hip_runtime.h>
#include <stdint.h>

#define DIMD 512
#define ROWS 65536

// ---- fused cooperative geometry: hold ALL weights on-chip ----
#define GRID  512
#define BLOCK 512               // 8 waves/block
#define WPB   8
#define RPW   16                // rows/wave: 12 in regs + 4 in LDS
#define REG_ROWS 12
#define LDS_ROWS 4              // 32 rows/block * 2 KiB = 64 KiB LDS

// ---- fallback (proven R3) geometry ----
#define FB_BLOCKS 2048
#define FB_WPB    4
#define FB_RPW    8

typedef float vfloat4 __attribute__((ext_vector_type(4)));

// ===========================================================================
// FUSED PATH (cooperative): phase 1 streams each weight row once from HBM,
// parks it on-chip (regs + LDS) while reducing the BMU distance; per-wave
// atomicMin into slots[block]. Hand-rolled grid barrier (device-scope
// arrive + spin; deadlock-free because cooperative launch guarantees
// co-residency). Phase 2: every wave reduces the 512 slots, then updates
// from the on-chip copy with nontemporal stores. 402 MB -> 268 MB traffic.
// ===========================================================================
__global__ __launch_bounds__(BLOCK, 4) void som_fused(
    const float* __restrict__ x,
    const float* __restrict__ w,
    const int* __restrict__ it_ptr,
    unsigned long long* __restrict__ slots,   // [GRID], memset 0xFF per call
    int* __restrict__ bar,                    // [2] = {cnt, flag}, memset 0
    float* __restrict__ out)
{
    __shared__ float lds[WPB * LDS_ROWS * DIMD];   // 64 KiB

    const int lane = threadIdx.x & 63;
    const int wave = threadIdx.x >> 6;
    const int row0 = (blockIdx.x * WPB + wave) * RPW;

    const float4* x4 = reinterpret_cast<const float4*>(x);
    const float4 xa = x4[lane];
    const float4 xb = x4[lane + 64];

    float4 ra[REG_ROWS], rb[REG_ROWS];
    unsigned long long best = ~0ull;

    #pragma unroll
    for (int r = 0; r < RPW; ++r) {
        const float4* w4 =
            reinterpret_cast<const float4*>(w + (size_t)(row0 + r) * DIMD);
        const float4 wa = w4[lane];
        const float4 wb = w4[lane + 64];
        if (r < REG_ROWS) {
            ra[r] = wa; rb[r] = wb;
        } else {
            float4* dst = reinterpret_cast<float4*>(
                lds + (wave * LDS_ROWS + (r - REG_ROWS)) * DIMD);
            dst[lane]      = wa;
            dst[lane + 64] = wb;
        }

        float s = 0.0f, t;
        t = wa.x - xa.x; s = fmaf(t, t, s);
        t = wa.y - xa.y; s = fmaf(t, t, s);
        t = wa.z - xa.z; s = fmaf(t, t, s);
        t = wa.w - xa.w; s = fmaf(t, t, s);
        t = wb.x - xb.x; s = fmaf(t, t, s);
        t = wb.y - xb.y; s = fmaf(t, t, s);
        t = wb.z - xb.z; s = fmaf(t, t, s);
        t = wb.w - xb.w; s = fmaf(t, t, s);

        #pragma unroll
        for (int off = 32; off > 0; off >>= 1)
            s += __shfl_xor(s, off, 64);

        const unsigned long long key =
            (((unsigned long long)__float_as_uint(s)) << 32) |
            (unsigned long long)(unsigned)(row0 + r);
        best = (key < best) ? key : best;
    }

    if (lane == 0) atomicMin(&slots[blockIdx.x], best);

    // ---- grid barrier: arrive (release) / spin (acquire) ----
    __syncthreads();
    if (threadIdx.x == 0) {
        __threadfence();   // make this block's atomicMin globally visible
        const int old = __hip_atomic_fetch_add(&bar[0], 1, __ATOMIC_ACQ_REL,
                                               __HIP_MEMORY_SCOPE_AGENT);
        if (old == GRID - 1) {
            __hip_atomic_store(&bar[1], 1, __ATOMIC_RELEASE,
                               __HIP_MEMORY_SCOPE_AGENT);
        } else {
            while (__hip_atomic_load(&bar[1], __ATOMIC_ACQUIRE,
                                     __HIP_MEMORY_SCOPE_AGENT) == 0) {
                __builtin_amdgcn_s_sleep(2);
            }
        }
        __threadfence();
    }
    __syncthreads();

    // ---- every wave reduces the 512 per-block candidates ----
    unsigned long long g = ~0ull;
    #pragma unroll
    for (int k = 0; k < GRID / 64; ++k) {
        const unsigned long long v = slots[k * 64 + lane];
        g = (v < g) ? v : g;
    }
    #pragma unroll
    for (int off = 32; off > 0; off >>= 1) {
        const unsigned long long o = __shfl_xor(g, off, 64);
        g = (o < g) ? o : g;
    }

    const unsigned bmu = (unsigned)(g & 0xFFFFFFFFull);
    const float bi = (float)(bmu >> 8);
    const float bj = (float)(bmu & 255u);

    const double itd      = (double)(*it_ptr);
    const double lr       = 1.0 - itd / 1000.0;
    const float  alpha_op = (float)(0.3 * lr);
    const double sigma_op = 128.0 * lr;            // SIGMA = max(M,N)/2
    const float  inv_s2   = (float)(1.0 / (sigma_op * sigma_op));

    float* winner      = out;
    float* new_weights = out + DIMD;

    #pragma unroll
    for (int r = 0; r < RPW; ++r) {
        const int row = row0 + r;
        const float di = (float)(row >> 8) - bi;
        const float dj = (float)(row & 255) - bj;
        const float coef = alpha_op * __expf(-(di * di + dj * dj) * inv_s2);

        float4 wa, wb;
        if (r < REG_ROWS) {
            wa = ra[r]; wb = rb[r];
        } else {
            const float4* src = reinterpret_cast<const float4*>(
                lds + (wave * LDS_ROWS + (r - REG_ROWS)) * DIMD);
            wa = src[lane];
            wb = src[lane + 64];
        }

        vfloat4 oa, ob;
        oa.x = fmaf(coef, xa.x - wa.x, wa.x);
        oa.y = fmaf(coef, xa.y - wa.y, wa.y);
        oa.z = fmaf(coef, xa.z - wa.z, wa.z);
        oa.w = fmaf(coef, xa.w - wa.w, wa.w);
        ob.x = fmaf(coef, xb.x - wb.x, wb.x);
        ob.y = fmaf(coef, xb.y - wb.y, wb.y);
        ob.z = fmaf(coef, xb.z - wb.z, wb.z);
        ob.w = fmaf(coef, xb.w - wb.w, wb.w);

        vfloat4* o4 =
            reinterpret_cast<vfloat4*>(new_weights + (size_t)row * DIMD);
        __builtin_nontemporal_store(oa, o4 + lane);
        __builtin_nontemporal_store(ob, o4 + lane + 64);

        if (row == (int)bmu) {
            float4* wn = reinterpret_cast<float4*>(winner);
            wn[lane]      = wa;
            wn[lane + 64] = wb;
        }
    }
}

// ===========================================================================
// FALLBACK PATH — byte-identical to the proven R3 two-kernel version.
// ===========================================================================
__global__ __launch_bounds__(256) void som_argmin_kernel(
    const float* __restrict__ x,
    const float* __restrict__ w,
    unsigned long long* __restrict__ slots)
{
    const int lane  = threadIdx.x & 63;
    const int wave  = threadIdx.x >> 6;
    const int gwave = blockIdx.x * FB_WPB + wave;
    const int row0  = gwave * FB_RPW;

    const float4* x4 = reinterpret_cast<const float4*>(x);
    const float4 xa = x4[lane];
    const float4 xb = x4[lane + 64];

    float d[FB_RPW];

    #pragma unroll
    for (int r = 0; r < FB_RPW; ++r) {
        const float4* w4 =
            reinterpret_cast<const float4*>(w + (size_t)(row0 + r) * DIMD);
        const float4 wa = w4[lane];
        const float4 wb = w4[lane + 64];

        float s = 0.0f, t;
        t = wa.x - xa.x; s = fmaf(t, t, s);
        t = wa.y - xa.y; s = fmaf(t, t, s);
        t = wa.z - xa.z; s = fmaf(t, t, s);
        t = wa.w - xa.w; s = fmaf(t, t, s);
        t = wb.x - xb.x; s = fmaf(t, t, s);
        t = wb.y - xb.y; s = fmaf(t, t, s);
        t = wb.z - xb.z; s = fmaf(t, t, s);
        t = wb.w - xb.w; s = fmaf(t, t, s);
        d[r] = s;
    }

    #pragma unroll
    for (int off = 32; off > 0; off >>= 1) {
        #pragma unroll
        for (int r = 0; r < FB_RPW; ++r)
            d[r] += __shfl_xor(d[r], off, 64);
    }

    unsigned long long best = ~0ull;
    #pragma unroll
    for (int r = 0; r < FB_RPW; ++r) {
        unsigned long long key =
            (((unsigned long long)__float_as_uint(d[r])) << 32) |
            (unsigned long long)(unsigned)(row0 + r);
        best = (key < best) ? key : best;
    }

    __shared__ unsigned long long sbest[FB_WPB];
    if (lane == 0) sbest[wave] = best;
    __syncthreads();
    if (threadIdx.x == 0) {
        unsigned long long b = sbest[0];
        #pragma unroll
        for (int i = 1; i < FB_WPB; ++i) b = (sbest[i] < b) ? sbest[i] : b;
        slots[blockIdx.x] = b;
    }
}

__global__ __launch_bounds__(256) void som_update_kernel(
    const float* __restrict__ x,
    const float* __restrict__ w,
    const int* __restrict__ it_ptr,
    const unsigned long long* __restrict__ slots,
    float* __restrict__ out)
{
    const int lane  = threadIdx.x & 63;
    const int wave  = threadIdx.x >> 6;

    unsigned long long b = ~0ull;
    for (int i = threadIdx.x; i < FB_BLOCKS; i += 256) {
        unsigned long long v = slots[i];
        b = (v < b) ? v : b;
    }
    #pragma unroll
    for (int off = 32; off > 0; off >>= 1) {
        unsigned long long o = __shfl_xor(b, off, 64);
        b = (o < b) ? o : b;
    }
    __shared__ unsigned long long sbest[FB_WPB];
    if (lane == 0) sbest[wave] = b;
    __syncthreads();
    unsigned long long g = sbest[0];
    #pragma unroll
    for (int i = 1; i < FB_WPB; ++i) g = (sbest[i] < g) ? sbest[i] : g;

    const unsigned bmu = (unsigned)(g & 0xFFFFFFFFull);
    const float bi = (float)(bmu >> 8);
    const float bj = (float)(bmu & 255u);

    const double itd      = (double)(*it_ptr);
    const double lr       = 1.0 - itd / 1000.0;
    const float  alpha_op = (float)(0.3 * lr);
    const double sigma_op = 128.0 * lr;
    const float  inv_s2   = (float)(1.0 / (sigma_op * sigma_op));

    const float4* x4 = reinterpret_cast<const float4*>(x);
    const float4 xa = x4[lane];
    const float4 xb = x4[lane + 64];

    float* winner      = out;
    float* new_weights = out + DIMD;

    const int gwave = blockIdx.x * FB_WPB + wave;
    const int row0  = gwave * FB_RPW;

    #pragma unroll
    for (int r = 0; r < FB_RPW; ++r) {
        const int row = row0 + r;
        const float di = (float)(row >> 8) - bi;
        const float dj = (float)(row & 255) - bj;
        const float coef = alpha_op * __expf(-(di * di + dj * dj) * inv_s2);

        const float4* w4 =
            reinterpret_cast<const float4*>(w + (size_t)row * DIMD);
        const float4 wa = w4[lane];
        const float4 wb = w4[lane + 64];

        vfloat4 oa, ob;
        oa.x = fmaf(coef, xa.x - wa.x, wa.x);
        oa.y = fmaf(coef, xa.y - wa.y, wa.y);
        oa.z = fmaf(coef, xa.z - wa.z, wa.z);
        oa.w = fmaf(coef, xa.w - wa.w, wa.w);
        ob.x = fmaf(coef, xb.x - wb.x, wb.x);
        ob.y = fmaf(coef, xb.y - wb.y, wb.y);
        ob.z = fmaf(coef, xb.z - wb.z, wb.z);
        ob.w = fmaf(coef, xb.w - wb.w, wb.w);

        vfloat4* o4 = reinterpret_cast<vfloat4*>(new_weights + (size_t)row * DIMD);
        __builtin_nontemporal_store(oa, o4 + lane);
        __builtin_nontemporal_store(ob, o4 + lane + 64);

        if (row == (int)bmu) {
            float4* wn = reinterpret_cast<float4*>(winner);
            wn[lane]      = wa;
            wn[lane + 64] = wb;
        }
    }
}

extern "C" void kernel_launch(void* const* d_in, const int* in_sizes, int n_in,
                              void* d_out, int out_size, void* d_ws, size_t ws_size,
                              hipStream_t stream) {
    const float* x       = (const float*)d_in[0];
    const float* weights = (const float*)d_in[1];
    const int*   it_ptr  = (const int*)d_in[3];
    float* out = (float*)d_out;

    // ws layout: [0,4096) coop slots | [4096,4104) barrier | [8192,+16K) fb slots
    unsigned long long* slots  = (unsigned long long*)d_ws;
    int*                bar    = (int*)((char*)d_ws + 4096);
    unsigned long long* slots2 = (unsigned long long*)((char*)d_ws + 8192);

    hipMemsetAsync(slots, 0xFF, GRID * sizeof(unsigned long long), stream);
    hipMemsetAsync(bar, 0, 2 * sizeof(int), stream);

    void* args[] = { (void*)&x, (void*)&weights, (void*)&it_ptr,
                     (void*)&slots, (void*)&bar, (void*)&out };
    hipError_t err = hipLaunchCooperativeKernel((const void*)som_fused,
                                                dim3(GRID), dim3(BLOCK),
                                                args, 0, stream);
    if (err != hipSuccess) {
        (void)hipGetLastError();   // clear sticky error state
        som_argmin_kernel<<<FB_BLOCKS, 256, 0, stream>>>(x, weights, slots2);
        som_update_kernel<<<FB_BLOCKS, 256, 0, stream>>>(x, weights, it_ptr,
                                                         slots2, out);
    }
}

// Round 6
// 184.254 us; speedup vs baseline: 1.0633x; 1.0633x over previous
//
#include <hip/hip_runtime.h>
#include <stdint.h>

#define DIMD 512
#define ROWS 65536

// ---- fused cooperative geometry ----
#define GRID  512
#define BLOCK 512               // 8 waves/block, 2 blocks/CU co-resident
#define WPB   8
#define RPW   16                // rows/wave: 8 regs + 4 LDS + 4 re-read
#define REG_ROWS 8              // 64 data VGPRs -> no spill under 128 cap
#define LDS_ROWS 4              // 32 rows/block * 2 KiB = 64 KiB LDS
#define ONCHIP   (REG_ROWS + LDS_ROWS)   // rows 12..15 re-read from L3

// ---- fallback (proven R3) geometry ----
#define FB_BLOCKS 2048
#define FB_WPB    4
#define FB_RPW    8

typedef float vfloat4 __attribute__((ext_vector_type(4)));

// ===========================================================================
// FUSED PATH (cooperative). Phase 1 streams each weight row once from HBM,
// parks 12/16 rows per wave on-chip (8 regs + 4 LDS) while reducing the BMU
// distance; per-wave atomicMin into slots[block]. Hand-rolled grid barrier.
// Phase 2: every wave reduces the 512 slots, then updates; rows 12..15 are
// re-read from global (they were streamed moments ago -> L3-resident).
// Traffic: 402 MB (2-kernel) -> ~268 MB HBM + 33 MB L3.
// NOTE: slots AND bar are memset 0xFF in one fill; the barrier runs from -1
// (cnt: old values seen are -1..510, last sees GRID-2; flag: spin while -1).
// ===========================================================================
__global__ __launch_bounds__(BLOCK, 4) void som_fused(
    const float* __restrict__ x,
    const float* __restrict__ w,
    const int* __restrict__ it_ptr,
    unsigned long long* __restrict__ slots,   // [GRID], memset 0xFF per call
    int* __restrict__ bar,                    // [2] = {cnt, flag}, 0xFF init
    float* __restrict__ out)
{
    __shared__ float lds[WPB * LDS_ROWS * DIMD];   // 64 KiB

    const int lane = threadIdx.x & 63;
    const int wave = threadIdx.x >> 6;
    const int row0 = (blockIdx.x * WPB + wave) * RPW;

    const float4* x4 = reinterpret_cast<const float4*>(x);
    const float4 xa = x4[lane];
    const float4 xb = x4[lane + 64];

    float4 ra[REG_ROWS], rb[REG_ROWS];
    unsigned long long best = ~0ull;

    #pragma unroll
    for (int r = 0; r < RPW; ++r) {
        const float4* w4 =
            reinterpret_cast<const float4*>(w + (size_t)(row0 + r) * DIMD);
        const float4 wa = w4[lane];
        const float4 wb = w4[lane + 64];
        if (r < REG_ROWS) {
            ra[r] = wa; rb[r] = wb;
        } else if (r < ONCHIP) {
            float4* dst = reinterpret_cast<float4*>(
                lds + (wave * LDS_ROWS + (r - REG_ROWS)) * DIMD);
            dst[lane]      = wa;
            dst[lane + 64] = wb;
        }
        // rows ONCHIP..RPW-1: distance only; re-read in phase 2 (L3 hit)

        float s = 0.0f, t;
        t = wa.x - xa.x; s = fmaf(t, t, s);
        t = wa.y - xa.y; s = fmaf(t, t, s);
        t = wa.z - xa.z; s = fmaf(t, t, s);
        t = wa.w - xa.w; s = fmaf(t, t, s);
        t = wb.x - xb.x; s = fmaf(t, t, s);
        t = wb.y - xb.y; s = fmaf(t, t, s);
        t = wb.z - xb.z; s = fmaf(t, t, s);
        t = wb.w - xb.w; s = fmaf(t, t, s);

        #pragma unroll
        for (int off = 32; off > 0; off >>= 1)
            s += __shfl_xor(s, off, 64);

        const unsigned long long key =
            (((unsigned long long)__float_as_uint(s)) << 32) |
            (unsigned long long)(unsigned)(row0 + r);
        best = (key < best) ? key : best;
    }

    if (lane == 0) atomicMin(&slots[blockIdx.x], best);

    // ---- grid barrier: arrive (release) / spin (acquire), -1-based ----
    __syncthreads();
    if (threadIdx.x == 0) {
        __threadfence();   // publish this block's atomicMin
        const int old = __hip_atomic_fetch_add(&bar[0], 1, __ATOMIC_ACQ_REL,
                                               __HIP_MEMORY_SCOPE_AGENT);
        if (old == GRID - 2) {          // cnt started at -1: last sees 510
            __hip_atomic_store(&bar[1], 1, __ATOMIC_RELEASE,
                               __HIP_MEMORY_SCOPE_AGENT);
        } else {
            while (__hip_atomic_load(&bar[1], __ATOMIC_ACQUIRE,
                                     __HIP_MEMORY_SCOPE_AGENT) == -1) {
                __builtin_amdgcn_s_sleep(2);
            }
        }
        __threadfence();
    }
    __syncthreads();

    // ---- every wave reduces the 512 per-block candidates ----
    unsigned long long g = ~0ull;
    #pragma unroll
    for (int k = 0; k < GRID / 64; ++k) {
        const unsigned long long v = slots[k * 64 + lane];
        g = (v < g) ? v : g;
    }
    #pragma unroll
    for (int off = 32; off > 0; off >>= 1) {
        const unsigned long long o = __shfl_xor(g, off, 64);
        g = (o < g) ? o : g;
    }

    const unsigned bmu = (unsigned)(g & 0xFFFFFFFFull);
    const float bi = (float)(bmu >> 8);
    const float bj = (float)(bmu & 255u);

    const double itd      = (double)(*it_ptr);
    const double lr       = 1.0 - itd / 1000.0;
    const float  alpha_op = (float)(0.3 * lr);
    const double sigma_op = 128.0 * lr;            // SIGMA = max(M,N)/2
    const float  inv_s2   = (float)(1.0 / (sigma_op * sigma_op));

    float* winner      = out;
    float* new_weights = out + DIMD;

    #pragma unroll
    for (int r = 0; r < RPW; ++r) {
        const int row = row0 + r;
        const float di = (float)(row >> 8) - bi;
        const float dj = (float)(row & 255) - bj;
        const float coef = alpha_op * __expf(-(di * di + dj * dj) * inv_s2);

        float4 wa, wb;
        if (r < REG_ROWS) {
            wa = ra[r]; wb = rb[r];
        } else if (r < ONCHIP) {
            const float4* src = reinterpret_cast<const float4*>(
                lds + (wave * LDS_ROWS + (r - REG_ROWS)) * DIMD);
            wa = src[lane];
            wb = src[lane + 64];
        } else {
            const float4* w4 =
                reinterpret_cast<const float4*>(w + (size_t)row * DIMD);
            wa = w4[lane];       // L3-resident re-read (w never written)
            wb = w4[lane + 64];
        }

        vfloat4 oa, ob;
        oa.x = fmaf(coef, xa.x - wa.x, wa.x);
        oa.y = fmaf(coef, xa.y - wa.y, wa.y);
        oa.z = fmaf(coef, xa.z - wa.z, wa.z);
        oa.w = fmaf(coef, xa.w - wa.w, wa.w);
        ob.x = fmaf(coef, xb.x - wb.x, wb.x);
        ob.y = fmaf(coef, xb.y - wb.y, wb.y);
        ob.z = fmaf(coef, xb.z - wb.z, wb.z);
        ob.w = fmaf(coef, xb.w - wb.w, wb.w);

        vfloat4* o4 =
            reinterpret_cast<vfloat4*>(new_weights + (size_t)row * DIMD);
        __builtin_nontemporal_store(oa, o4 + lane);
        __builtin_nontemporal_store(ob, o4 + lane + 64);

        if (row == (int)bmu) {
            float4* wn = reinterpret_cast<float4*>(winner);
            wn[lane]      = wa;   // OLD weights row
            wn[lane + 64] = wb;
        }
    }
}

// ===========================================================================
// FALLBACK PATH — byte-identical to the proven R3 two-kernel version.
// ===========================================================================
__global__ __launch_bounds__(256) void som_argmin_kernel(
    const float* __restrict__ x,
    const float* __restrict__ w,
    unsigned long long* __restrict__ slots)
{
    const int lane  = threadIdx.x & 63;
    const int wave  = threadIdx.x >> 6;
    const int gwave = blockIdx.x * FB_WPB + wave;
    const int row0  = gwave * FB_RPW;

    const float4* x4 = reinterpret_cast<const float4*>(x);
    const float4 xa = x4[lane];
    const float4 xb = x4[lane + 64];

    float d[FB_RPW];

    #pragma unroll
    for (int r = 0; r < FB_RPW; ++r) {
        const float4* w4 =
            reinterpret_cast<const float4*>(w + (size_t)(row0 + r) * DIMD);
        const float4 wa = w4[lane];
        const float4 wb = w4[lane + 64];

        float s = 0.0f, t;
        t = wa.x - xa.x; s = fmaf(t, t, s);
        t = wa.y - xa.y; s = fmaf(t, t, s);
        t = wa.z - xa.z; s = fmaf(t, t, s);
        t = wa.w - xa.w; s = fmaf(t, t, s);
        t = wb.x - xb.x; s = fmaf(t, t, s);
        t = wb.y - xb.y; s = fmaf(t, t, s);
        t = wb.z - xb.z; s = fmaf(t, t, s);
        t = wb.w - xb.w; s = fmaf(t, t, s);
        d[r] = s;
    }

    #pragma unroll
    for (int off = 32; off > 0; off >>= 1) {
        #pragma unroll
        for (int r = 0; r < FB_RPW; ++r)
            d[r] += __shfl_xor(d[r], off, 64);
    }

    unsigned long long best = ~0ull;
    #pragma unroll
    for (int r = 0; r < FB_RPW; ++r) {
        unsigned long long key =
            (((unsigned long long)__float_as_uint(d[r])) << 32) |
            (unsigned long long)(unsigned)(row0 + r);
        best = (key < best) ? key : best;
    }

    __shared__ unsigned long long sbest[FB_WPB];
    if (lane == 0) sbest[wave] = best;
    __syncthreads();
    if (threadIdx.x == 0) {
        unsigned long long b = sbest[0];
        #pragma unroll
        for (int i = 1; i < FB_WPB; ++i) b = (sbest[i] < b) ? sbest[i] : b;
        slots[blockIdx.x] = b;
    }
}

__global__ __launch_bounds__(256) void som_update_kernel(
    const float* __restrict__ x,
    const float* __restrict__ w,
    const int* __restrict__ it_ptr,
    const unsigned long long* __restrict__ slots,
    float* __restrict__ out)
{
    const int lane  = threadIdx.x & 63;
    const int wave  = threadIdx.x >> 6;

    unsigned long long b = ~0ull;
    for (int i = threadIdx.x; i < FB_BLOCKS; i += 256) {
        unsigned long long v = slots[i];
        b = (v < b) ? v : b;
    }
    #pragma unroll
    for (int off = 32; off > 0; off >>= 1) {
        unsigned long long o = __shfl_xor(b, off, 64);
        b = (o < b) ? o : b;
    }
    __shared__ unsigned long long sbest[FB_WPB];
    if (lane == 0) sbest[wave] = b;
    __syncthreads();
    unsigned long long g = sbest[0];
    #pragma unroll
    for (int i = 1; i < FB_WPB; ++i) g = (sbest[i] < g) ? sbest[i] : g;

    const unsigned bmu = (unsigned)(g & 0xFFFFFFFFull);
    const float bi = (float)(bmu >> 8);
    const float bj = (float)(bmu & 255u);

    const double itd      = (double)(*it_ptr);
    const double lr       = 1.0 - itd / 1000.0;
    const float  alpha_op = (float)(0.3 * lr);
    const double sigma_op = 128.0 * lr;
    const float  inv_s2   = (float)(1.0 / (sigma_op * sigma_op));

    const float4* x4 = reinterpret_cast<const float4*>(x);
    const float4 xa = x4[lane];
    const float4 xb = x4[lane + 64];

    float* winner      = out;
    float* new_weights = out + DIMD;

    const int gwave = blockIdx.x * FB_WPB + wave;
    const int row0  = gwave * FB_RPW;

    #pragma unroll
    for (int r = 0; r < FB_RPW; ++r) {
        const int row = row0 + r;
        const float di = (float)(row >> 8) - bi;
        const float dj = (float)(row & 255) - bj;
        const float coef = alpha_op * __expf(-(di * di + dj * dj) * inv_s2);

        const float4* w4 =
            reinterpret_cast<const float4*>(w + (size_t)row * DIMD);
        const float4 wa = w4[lane];
        const float4 wb = w4[lane + 64];

        vfloat4 oa, ob;
        oa.x = fmaf(coef, xa.x - wa.x, wa.x);
        oa.y = fmaf(coef, xa.y - wa.y, wa.y);
        oa.z = fmaf(coef, xa.z - wa.z, wa.z);
        oa.w = fmaf(coef, xa.w - wa.w, wa.w);
        ob.x = fmaf(coef, xb.x - wb.x, wb.x);
        ob.y = fmaf(coef, xb.y - wb.y, wb.y);
        ob.z = fmaf(coef, xb.z - wb.z, wb.z);
        ob.w = fmaf(coef, xb.w - wb.w, wb.w);

        vfloat4* o4 = reinterpret_cast<vfloat4*>(new_weights + (size_t)row * DIMD);
        __builtin_nontemporal_store(oa, o4 + lane);
        __builtin_nontemporal_store(ob, o4 + lane + 64);

        if (row == (int)bmu) {
            float4* wn = reinterpret_cast<float4*>(winner);
            wn[lane]      = wa;
            wn[lane + 64] = wb;
        }
    }
}

extern "C" void kernel_launch(void* const* d_in, const int* in_sizes, int n_in,
                              void* d_out, int out_size, void* d_ws, size_t ws_size,
                              hipStream_t stream) {
    const float* x       = (const float*)d_in[0];
    const float* weights = (const float*)d_in[1];
    const int*   it_ptr  = (const int*)d_in[3];
    float* out = (float*)d_out;

    // ws layout: [0,4096) coop slots | [4096,4104) barrier | [8192,+16K) fb slots
    unsigned long long* slots  = (unsigned long long*)d_ws;
    int*                bar    = (int*)((char*)d_ws + 4096);
    unsigned long long* slots2 = (unsigned long long*)((char*)d_ws + 8192);

    // ONE fill covers slots (0xFF.. = +inf keys) AND bar (cnt=-1, flag=-1).
    hipMemsetAsync(d_ws, 0xFF, 4096 + 2 * sizeof(int), stream);

    void* args[] = { (void*)&x, (void*)&weights, (void*)&it_ptr,
                     (void*)&slots, (void*)&bar, (void*)&out };
    hipError_t err = hipLaunchCooperativeKernel((const void*)som_fused,
                                                dim3(GRID), dim3(BLOCK),
                                                args, 0, stream);
    if (err != hipSuccess) {
        (void)hipGetLastError();   // clear sticky error state
        som_argmin_kernel<<<FB_BLOCKS, 256, 0, stream>>>(x, weights, slots2);
        som_update_kernel<<<FB_BLOCKS, 256, 0, stream>>>(x, weights, it_ptr,
                                                         slots2, out);
    }
}